// Round 17
// baseline (415.122 us; speedup 1.0000x reference)
//
#include <hip/hip_runtime.h>
#include <hip/hip_bf16.h>

// ---------------------------------------------------------------------------
// WindowShiftedMDTA, v17 (MI355X / gfx950).
//
// Math fact: with shift = window/2 the reference's shift-mask is all ones =>
// output == unshifted branch only.  fp32 I/O, bf16 MFMA compute (validated:
// absmax 4.9e-4 vs threshold 1.79e-3).
//
// v16 (=v14, 184.5us) post-mortem: all kernels run at 1-2.3 TB/s with
// occupancy capped at 4 blocks/CU by __launch_bounds__(256,4), though
// resources allow 6-8.  v17 = v16 with ONLY the launch-bounds raised:
// g0 (12 VGPR) -> (256,8); g1/attn2/k2 (64 VGPR) -> (256,6) (VGPR cap 85,
// no spill risk).  Everything else byte-identical to the validated v16.
// ---------------------------------------------------------------------------

typedef short bf16x4 __attribute__((ext_vector_type(4)));
typedef short bf16x8 __attribute__((ext_vector_type(8)));
typedef float f32x4  __attribute__((ext_vector_type(4)));
typedef unsigned short ushort_t;

#define MFMA_K16(A_, B_, C_) __builtin_amdgcn_mfma_f32_16x16x16bf16_1k((A_), (B_), (C_), 0, 0, 0)
#define MFMA_K32(A_, B_, C_) __builtin_amdgcn_mfma_f32_16x16x32_bf16((A_), (B_), (C_), 0, 0, 0)

__device__ __forceinline__ short f2b(float f) {
  __hip_bfloat16 h = __float2bfloat16(f);
  return __builtin_bit_cast(short, h);
}
__device__ __forceinline__ bf16x4 cvt4(f32x4 v, float sc) {
  bf16x4 r;
  r[0] = f2b(v[0] * sc); r[1] = f2b(v[1] * sc);
  r[2] = f2b(v[2] * sc); r[3] = f2b(v[3] * sc);
  return r;
}
__device__ __forceinline__ int PI(int p) { return (p ^ (p >> 3)) & 7; }

template<bool B16>
__device__ __forceinline__ bf16x8 ldw8(const void* W, int row, int c0) {
  if constexpr (B16) {
    return *(const bf16x8*)((const ushort_t*)W + (row << 8) + c0);
  } else {
    const float* p = (const float*)W + (row << 8) + c0;
    const float4 x = *(const float4*)p, y = *(const float4*)(p + 4);
    bf16x8 f;
    f[0] = f2b(x.x); f[1] = f2b(x.y); f[2] = f2b(x.z); f[3] = f2b(x.w);
    f[4] = f2b(y.x); f[5] = f2b(y.y); f[6] = f2b(y.z); f[7] = f2b(y.w);
    return f;
  }
}
__device__ __forceinline__ bf16x8 ldw8b(const ushort_t* W, int row, int c0) {
  return *(const bf16x8*)(W + (row << 8) + c0);
}

constexpr size_t BUFE = 9437184;                 // 256 c x 36864 px (1 batch)

__global__ void wconv(const float* __restrict__ a, const float* __restrict__ b,
                      const float* __restrict__ c, const float* __restrict__ d,
                      ushort_t* __restrict__ o) {
  const int gid = blockIdx.x * 256 + threadIdx.x;
  const int which = gid >> 14;
  const int idx = (gid & 16383) * 4;
  const float* src = which == 0 ? a : which == 1 ? b : which == 2 ? c : d;
  const float4 v = *(const float4*)(src + idx);
  bf16x4 w; w[0] = f2b(v.x); w[1] = f2b(v.y); w[2] = f2b(v.z); w[3] = f2b(v.w);
  *(bf16x4*)(o + which * 65536 + idx) = w;
}

// ======================= g0_xt: x [c][px] f32 -> xT [px][c] bf16 ===========
__global__ __launch_bounds__(256, 8) void g0_xt(
    const float* __restrict__ xq, const float* __restrict__ xkv,
    ushort_t* __restrict__ xtq, ushort_t* __restrict__ xtkv, int bbase)
{
  __shared__ __align__(16) ushort_t tile[64 * 72];
  const int tid = threadIdx.x;
  const int id = (blockIdx.x & 7) * (gridDim.x >> 3) + (blockIdx.x >> 3);
  int r = id;
  const int pxt = r % 576; r /= 576;
  const int ct = r & 3; r >>= 2;
  const int which = r & 1;
  const int bl = r >> 1;
  const float* src = which ? xkv : xq;
  ushort_t* dst = which ? xtkv : xtq;
  const size_t gib = (size_t)(bbase + bl) * BUFE;

  {
    const int cr = tid >> 2, seg = tid & 3;
    const float* p = src + gib + (size_t)(ct * 64 + cr) * 36864 + pxt * 64 + seg * 16;
    const float4 f0 = *(const float4*)p,       f1 = *(const float4*)(p + 4);
    const float4 f2 = *(const float4*)(p + 8), f3 = *(const float4*)(p + 12);
    bf16x8 a, b;
    a[0]=f2b(f0.x); a[1]=f2b(f0.y); a[2]=f2b(f0.z); a[3]=f2b(f0.w);
    a[4]=f2b(f1.x); a[5]=f2b(f1.y); a[6]=f2b(f1.z); a[7]=f2b(f1.w);
    b[0]=f2b(f2.x); b[1]=f2b(f2.y); b[2]=f2b(f2.z); b[3]=f2b(f2.w);
    b[4]=f2b(f3.x); b[5]=f2b(f3.y); b[6]=f2b(f3.z); b[7]=f2b(f3.w);
    *(bf16x8*)(tile + cr * 72 + seg * 16) = a;
    *(bf16x8*)(tile + cr * 72 + seg * 16 + 8) = b;
  }
  __syncthreads();
  {
    const int opx = tid >> 2, oseg = tid & 3;
    bf16x8 a, b;
    #pragma unroll
    for (int j = 0; j < 8; ++j) a[j] = tile[(oseg * 16 + j) * 72 + opx];
    #pragma unroll
    for (int j = 0; j < 8; ++j) b[j] = tile[(oseg * 16 + 8 + j) * 72 + opx];
    ushort_t* q = dst + (size_t)bl * BUFE + (size_t)(pxt * 64 + opx) * 256 + ct * 64 + oseg * 16;
    *(bf16x8*)q = a;
    *(bf16x8*)(q + 8) = b;
  }
}

// ======================= g1_qkv: q,k,v = W . x =============================
__global__ __launch_bounds__(256, 6) void g1_qkv(
    const ushort_t* __restrict__ xtq, const ushort_t* __restrict__ xtkv,
    const ushort_t* __restrict__ Wq, const ushort_t* __restrict__ Wk,
    const ushort_t* __restrict__ Wv,
    ushort_t* __restrict__ qbuf, ushort_t* __restrict__ kbuf,
    ushort_t* __restrict__ vimg)
{
  __shared__ __align__(16) char smem[26624];     // stage 24576 | v-stash 26624
  const int tid = threadIdx.x, lane = tid & 63, wv4 = tid >> 6;
  const int l15 = lane & 15, g = lane >> 4;

  const int wid = (blockIdx.x & 7) * (gridDim.x >> 3) + (blockIdx.x >> 3);
  const int ct = wid % 6;
  int r = wid / 6;
  const int whalf = r & 1; r >>= 1;
  const int h = r % 192;
  const int bl = r / 192;
  const int ph = h & 7;
  const int winbase = bl * 576 + (h >> 3) * 24 + whalf * 12;
  const int pxrow = h * 192 + whalf * 96;

  const int mode = ct >> 1;                      // 0=q,1=k,2=v
  const ushort_t* xs = ((mode == 0) ? xtq : xtkv) + (size_t)bl * BUFE;
  const ushort_t* W  = (mode == 0) ? Wq : (mode == 1) ? Wk : Wv;
  const int chalf = (ct & 1) * 128;
  const int cobase = chalf + wv4 * 32;

  f32x4 acc[6][2];
  #pragma unroll
  for (int nt = 0; nt < 6; ++nt) { acc[nt][0] = {0,0,0,0}; acc[nt][1] = {0,0,0,0}; }

  #pragma unroll
  for (int ki = 0; ki < 2; ++ki) {
    bf16x8 wf[4][2];
    #pragma unroll
    for (int sk = 0; sk < 4; ++sk) {
      const int c0 = ki * 128 + sk * 32 + g * 8;
      wf[sk][0] = ldw8b(W, cobase + l15,      c0);
      wf[sk][1] = ldw8b(W, cobase + 16 + l15, c0);
    }
    if (ki) __syncthreads();
    #pragma unroll
    for (int j = 0; j < 6; ++j) {
      const int u = j * 256 + tid;
      const int t = u >> 4, ch = u & 15;
      const bf16x8 v = *(const bf16x8*)(xs + (size_t)(pxrow + t) * 256 + ki * 128 + ch * 8);
      const int sl = ch ^ (t & 7);
      *(bf16x8*)(smem + (unsigned)(t * 256 + sl * 16)) = v;
    }
    __syncthreads();
    #pragma unroll
    for (int sk = 0; sk < 4; ++sk) {
      #pragma unroll
      for (int nt = 0; nt < 6; ++nt) {
        const int t = nt * 16 + l15;
        const int lch = sk * 4 + g;
        const bf16x8 af = *(const bf16x8*)(smem + (unsigned)(t * 256 + ((lch ^ (t & 7)) << 4)));
        if (mode < 2) {
          acc[nt][0] = MFMA_K32(wf[sk][0], af, acc[nt][0]);  // C: col=px, rows=co
          acc[nt][1] = MFMA_K32(wf[sk][1], af, acc[nt][1]);
        } else {
          acc[nt][0] = MFMA_K32(af, wf[sk][0], acc[nt][0]);  // C: col=d, rows=px
          acc[nt][1] = MFMA_K32(af, wf[sk][1], acc[nt][1]);
        }
      }
    }
  }
  __syncthreads();                               // LDS tile now dead -> stash

  if (mode < 2) {
    #pragma unroll
    for (int nt = 0; nt < 6; ++nt)
      #pragma unroll
      for (int cj = 0; cj < 2; ++cj) {
        const int t = nt * 16 + l15;
        const int bb = (wv4 * 4 + cj * 2 + (g >> 1)) ^ (t & 7);
        *(bf16x4*)(smem + (unsigned)(t * 256 + bb * 16 + (g & 1) * 8)) = cvt4(acc[nt][cj], 1.f);
      }
    __syncthreads();
    ushort_t* dst = (mode == 0) ? qbuf : kbuf;
    #pragma unroll
    for (int j = 0; j < 6; ++j) {
      const int u = j * 256 + tid;
      const int t = u >> 4, ch = u & 15;
      const bf16x8 v = *(const bf16x8*)(smem + (unsigned)(t * 256 + ((ch ^ (t & 7)) << 4)));
      const int win = winbase + (t >> 3);
      const int pos = ph * 8 + (t & 7);
      *(bf16x8*)(dst + (size_t)win * 16384 + pos * 256 + chalf + ch * 8) = v;
    }
  } else {
    #pragma unroll
    for (int nt = 0; nt < 6; ++nt)
      #pragma unroll
      for (int dj = 0; dj < 2; ++dj) {
        const int dl = wv4 * 32 + dj * 16 + l15;
        *(bf16x4*)(smem + (unsigned)(dl * 208 + (nt * 16 + 4 * g) * 2)) = cvt4(acc[nt][dj], 1.f);
      }
    __syncthreads();
    #pragma unroll
    for (int j = 0; j < 6; ++j) {
      const int u = j * 256 + tid;
      const int dl = u / 12, ch = u - dl * 12;
      const bf16x8 v = *(const bf16x8*)(smem + (unsigned)(dl * 208 + ch * 16));
      *(bf16x8*)(vimg + (size_t)bl * BUFE + (size_t)(chalf + dl) * 36864 + pxrow + ch * 8) = v;
    }
  }
}

// ======================= attn2: per-(win,head) attention ===================
__global__ __launch_bounds__(256, 6) void attn2(
    const float* __restrict__ temp,
    const ushort_t* __restrict__ qbuf, const ushort_t* __restrict__ kbuf,
    const ushort_t* __restrict__ vimg, ushort_t* __restrict__ abuf)
{
  const int tid = threadIdx.x, lane = tid & 63, wv4 = tid >> 6;
  const int l15 = lane & 15, g = lane >> 4;

  const int wid = (blockIdx.x & 7) * (gridDim.x >> 3) + (blockIdx.x >> 3);
  const int hg = wid & 1;
  const int winL = wid >> 1;
  const int bl = winL / 576, rw = winL % 576;
  const int wh = rw / 24, ww = rw % 24;
  const int h = hg * 4 + wv4;
  const float tm = temp[h];
  const size_t wb = (size_t)winL * 16384;
  const int hb = h * 32;
  const f32x4 fzero = {0.f, 0.f, 0.f, 0.f};

  bf16x8 qf[4], kf[4];
  #pragma unroll
  for (int i = 0; i < 4; ++i) {
    qf[i] = *(const bf16x8*)(qbuf + wb + (i * 16 + l15) * 256 + hb + g * 8);
    kf[i] = *(const bf16x8*)(kbuf + wb + (i * 16 + l15) * 256 + hb + g * 8);
  }
  f32x4 s[4][4];
  #pragma unroll
  for (int mt = 0; mt < 4; ++mt)
    #pragma unroll
    for (int nt = 0; nt < 4; ++nt)
      s[mt][nt] = MFMA_K32(kf[mt], qf[nt], fzero);   // C[m][n], col=n

  bf16x4 Pb[4][4];
  #pragma unroll
  for (int nt = 0; nt < 4; ++nt) {
    float mx = -1e30f;
    #pragma unroll
    for (int mt = 0; mt < 4; ++mt)
      #pragma unroll
      for (int rr = 0; rr < 4; ++rr) {
        const float v = s[mt][nt][rr] * tm;
        s[mt][nt][rr] = v;
        mx = fmaxf(mx, v);
      }
    mx = fmaxf(mx, __shfl_xor(mx, 16));
    mx = fmaxf(mx, __shfl_xor(mx, 32));
    float sum = 0.f;
    #pragma unroll
    for (int mt = 0; mt < 4; ++mt)
      #pragma unroll
      for (int rr = 0; rr < 4; ++rr) {
        const float p = __expf(s[mt][nt][rr] - mx);
        s[mt][nt][rr] = p;
        sum += p;
      }
    sum += __shfl_xor(sum, 16);
    sum += __shfl_xor(sum, 32);
    const float ri = 1.f / sum;
    #pragma unroll
    for (int mt = 0; mt < 4; ++mt) Pb[mt][nt] = cvt4(s[mt][nt], ri);
  }

  f32x4 pcd[2][4];
  #pragma unroll
  for (int dj = 0; dj < 2; ++dj)
    #pragma unroll
    for (int nt = 0; nt < 4; ++nt) pcd[dj][nt] = fzero;
  #pragma unroll
  for (int mt = 0; mt < 4; ++mt)
    #pragma unroll
    for (int dj = 0; dj < 2; ++dj) {
      const int d = hb + dj * 16 + l15;
      const bf16x4 vf = *(const bf16x4*)(vimg + (size_t)bl * BUFE + (size_t)d * 36864
                        + (wh * 8 + 2 * mt + (g >> 1)) * 192 + ww * 8 + 4 * (g & 1));
      #pragma unroll
      for (int nt = 0; nt < 4; ++nt)
        pcd[dj][nt] = MFMA_K16(vf, Pb[mt][nt], pcd[dj][nt]);  // C[d][n]
    }

  #pragma unroll
  for (int dj = 0; dj < 2; ++dj)
    #pragma unroll
    for (int nt = 0; nt < 4; ++nt) {
      const int pos = nt * 16 + l15;
      const int c0 = hb + dj * 16 + 4 * g;
      *(bf16x4*)(abuf + wb + pos * 256 + c0) = cvt4(pcd[dj][nt], 1.f);
    }
}

// ======================= k2: out = Wo . A (image layout) ===================
__global__ __launch_bounds__(256, 6) void k2_out(
    const ushort_t* __restrict__ Wo, const ushort_t* __restrict__ abuf,
    float* __restrict__ out, int bbase)
{
  __shared__ __align__(16) char smem[24576];
  const int tid = threadIdx.x, lane = tid & 63, wv4 = tid >> 6;
  const int l15 = lane & 15, g = lane >> 4;

  const int wid = (blockIdx.x & 7) * (gridDim.x >> 3) + (blockIdx.x >> 3);
  const int ct = wid & 1;
  int r = wid >> 1;
  const int whalf = r & 1; r >>= 1;
  const int h = r % 192, bl = r / 192;
  const int wh = h >> 3, ph = h & 7, wstart = whalf * 96;
  const int winbase = bl * 576 + wh * 24 + (wstart >> 3);

  f32x4 acc[6][2];
  #pragma unroll
  for (int nt = 0; nt < 6; ++nt) { acc[nt][0] = {0,0,0,0}; acc[nt][1] = {0,0,0,0}; }

  const int corow0 = ct * 128 + wv4 * 32 + l15;

  #pragma unroll
  for (int ki = 0; ki < 2; ++ki) {
    const int kb = ki * 128;
    if (ki) __syncthreads();
    #pragma unroll
    for (int j = 0; j < 6; ++j) {
      const int u = j * 256 + tid;
      const int t = u >> 4, ch = u & 15;
      const int win = winbase + (t >> 3);
      const int wpos = ph * 8 + (t & 7);
      const bf16x8 v = *(const bf16x8*)(abuf + (size_t)win * 16384 + wpos * 256 + kb + ch * 8);
      const int sl = ch ^ (t & 7);
      *(bf16x8*)(smem + (unsigned)(t * 256 + sl * 16)) = v;
    }
    __syncthreads();
    #pragma unroll
    for (int sk = 0; sk < 4; ++sk) {
      const int c0 = kb + sk * 32 + g * 8;
      const bf16x8 w0 = ldw8b(Wo, corow0,      c0);
      const bf16x8 w1 = ldw8b(Wo, corow0 + 16, c0);
      #pragma unroll
      for (int nt = 0; nt < 6; ++nt) {
        const int t = nt * 16 + l15;
        const int lch = sk * 4 + g;
        const bf16x8 af = *(const bf16x8*)(smem + (unsigned)(t * 256 + ((lch ^ (t & 7)) << 4)));
        acc[nt][0] = MFMA_K32(w0, af, acc[nt][0]);
        acc[nt][1] = MFMA_K32(w1, af, acc[nt][1]);
      }
    }
  }

  #pragma unroll
  for (int nt = 0; nt < 6; ++nt)
    #pragma unroll
    for (int cj = 0; cj < 2; ++cj) {
      const int t = nt * 16 + l15;
      #pragma unroll
      for (int rr = 0; rr < 4; ++rr) {
        const int co = ct * 128 + wv4 * 32 + cj * 16 + 4 * g + rr;
        out[(size_t)(bbase + bl) * BUFE + (size_t)co * 36864 + h * 192 + wstart + t]
            = acc[nt][cj][rr];
      }
    }
}

// ================= v6 fallback (validated, 276us) ==========================
constexpr int SMEM_OLD = 65536;

template<int NT>
__device__ __forceinline__ void stage_half(char* dst, const float* __restrict__ src,
                                           int coff, int tid, size_t ibase, int xoff) {
  #pragma unroll
  for (int j = 0; j < 1024 / NT; ++j) {
    const int u = j * NT + tid;
    const int c = u >> 3, hr = u & 7;
    const size_t gg = ibase + (size_t)(c + coff) * 36864 + (size_t)(xoff + hr * 192);
    const float4 a0 = *(const float4*)(src + gg);
    const float4 a1 = *(const float4*)(src + gg + 4);
    const float vv[8] = {a0.x, a0.y, a0.z, a0.w, a1.x, a1.y, a1.z, a1.w};
    #pragma unroll
    for (int w = 0; w < 8; ++w) {
      const int pos = hr * 8 + w;
      const unsigned ad = (unsigned)(pos * 256 + (((c >> 3) ^ PI(pos)) << 4) + (c & 7) * 2);
      *(short*)(dst + ad) = f2b(vv[w]);
    }
  }
}
__device__ __forceinline__ bf16x8 xfrag8(const char* base, int kt, int nt, int l15, int g) {
  const int pos = nt * 16 + l15;
  const int c0 = kt * 32 + g * 8;
  const unsigned ad = (unsigned)(pos * 256 + (((c0 >> 3) ^ PI(pos)) << 4));
  return *(const bf16x8*)(base + ad);
}

template<bool WB16>
__global__ __launch_bounds__(512, 4) void wsmdta_old(
    const float* __restrict__ xq, const float* __restrict__ xkv,
    const float* __restrict__ temp,
    const void* __restrict__ Wq, const void* __restrict__ Wk,
    const void* __restrict__ Wv, const void* __restrict__ Wo,
    float* __restrict__ out)
{
  extern __shared__ __align__(16) char smem[];
  const int tid = threadIdx.x, lane = tid & 63, wv = tid >> 6;
  const int l15 = lane & 15, g = lane >> 4;
  const int bid = blockIdx.x;
  const int wid = (bid & 7) * 144 + (bid >> 3);
  const int b  = wid / 576, rw = wid - b * 576;
  const int wh = rw / 24,   ww = rw - wh * 24;
  const int xoff = wh * 1536 + ww * 8;
  const size_t ibase = (size_t)b * BUFE;
  const unsigned VB = 32768u + (unsigned)wv * 4096u;
  const f32x4 fzero = {0.f, 0.f, 0.f, 0.f};
  const int h = wv;
  const float tm = temp[h];

  f32x4 qcd[2][4];
  #pragma unroll
  for (int dj = 0; dj < 2; ++dj)
    #pragma unroll
    for (int nt = 0; nt < 4; ++nt) qcd[dj][nt] = fzero;
  #pragma unroll
  for (int half = 0; half < 2; ++half) {
    if (half) __syncthreads();
    stage_half<512>(smem, xq, half * 128, tid, ibase, xoff);
    __syncthreads();
    const int cg = half * 128;
    #pragma unroll
    for (int kt = 0; kt < 4; ++kt) {
      const bf16x8 w0 = ldw8<WB16>(Wq, h * 32 + l15,      cg + kt * 32 + g * 8);
      const bf16x8 w1 = ldw8<WB16>(Wq, h * 32 + 16 + l15, cg + kt * 32 + g * 8);
      #pragma unroll
      for (int nt = 0; nt < 4; ++nt) {
        const bf16x8 xf = xfrag8(smem, kt, nt, l15, g);
        qcd[0][nt] = MFMA_K32(w0, xf, qcd[0][nt]);
        qcd[1][nt] = MFMA_K32(w1, xf, qcd[1][nt]);
      }
    }
    __syncthreads();
  }
  bf16x4 qb[2][4];
  #pragma unroll
  for (int dj = 0; dj < 2; ++dj)
    #pragma unroll
    for (int nt = 0; nt < 4; ++nt) qb[dj][nt] = cvt4(qcd[dj][nt], 1.f);

  f32x4 kcd[2][4], vcd[2][4];
  #pragma unroll
  for (int dj = 0; dj < 2; ++dj)
    #pragma unroll
    for (int nt = 0; nt < 4; ++nt) { kcd[dj][nt] = fzero; vcd[dj][nt] = fzero; }
  #pragma unroll
  for (int half = 0; half < 2; ++half) {
    stage_half<512>(smem, xkv, half * 128, tid, ibase, xoff);
    __syncthreads();
    const int cg = half * 128;
    #pragma unroll
    for (int kt = 0; kt < 4; ++kt) {
      const bf16x8 wk0 = ldw8<WB16>(Wk, h * 32 + l15,      cg + kt * 32 + g * 8);
      const bf16x8 wk1 = ldw8<WB16>(Wk, h * 32 + 16 + l15, cg + kt * 32 + g * 8);
      const bf16x8 wv0 = ldw8<WB16>(Wv, h * 32 + l15,      cg + kt * 32 + g * 8);
      const bf16x8 wv1 = ldw8<WB16>(Wv, h * 32 + 16 + l15, cg + kt * 32 + g * 8);
      #pragma unroll
      for (int np = 0; np < 2; ++np) {
        const bf16x8 xf0 = xfrag8(smem, kt, np * 2,     l15, g);
        const bf16x8 xf1 = xfrag8(smem, kt, np * 2 + 1, l15, g);
        kcd[0][np*2]   = MFMA_K32(wk0, xf0, kcd[0][np*2]);
        kcd[1][np*2]   = MFMA_K32(wk1, xf0, kcd[1][np*2]);
        vcd[0][np*2]   = MFMA_K32(wv0, xf0, vcd[0][np*2]);
        vcd[1][np*2]   = MFMA_K32(wv1, xf0, vcd[1][np*2]);
        kcd[0][np*2+1] = MFMA_K32(wk0, xf1, kcd[0][np*2+1]);
        kcd[1][np*2+1] = MFMA_K32(wk1, xf1, kcd[1][np*2+1]);
        vcd[0][np*2+1] = MFMA_K32(wv0, xf1, vcd[0][np*2+1]);
        vcd[1][np*2+1] = MFMA_K32(wv1, xf1, vcd[1][np*2+1]);
      }
    }
    if (half == 0) __syncthreads();
  }
  bf16x4 kb[2][4];
  #pragma unroll
  for (int dj = 0; dj < 2; ++dj)
    #pragma unroll
    for (int mt = 0; mt < 4; ++mt) kb[dj][mt] = cvt4(kcd[dj][mt], 1.f);
  #pragma unroll
  for (int dj = 0; dj < 2; ++dj)
    #pragma unroll
    for (int mt = 0; mt < 4; ++mt) {
      const bf16x4 q = cvt4(vcd[dj][mt], 1.f);
      const int m = mt * 16 + l15;
      #pragma unroll
      for (int rr = 0; rr < 4; ++rr) {
        const int d = dj * 16 + 4 * g + rr;
        const unsigned ad = VB + (unsigned)(d * 128 + (((m >> 3) ^ (d & 7)) << 4) + (m & 7) * 2);
        *(short*)(smem + ad) = q[rr];
      }
    }
  f32x4 s[4][4];
  #pragma unroll
  for (int mt = 0; mt < 4; ++mt)
    #pragma unroll
    for (int nt = 0; nt < 4; ++nt) {
      s[mt][nt] = MFMA_K16(kb[0][mt], qb[0][nt], fzero);
      s[mt][nt] = MFMA_K16(kb[1][mt], qb[1][nt], s[mt][nt]);
    }
  bf16x4 Pb[4][4];
  #pragma unroll
  for (int nt = 0; nt < 4; ++nt) {
    float mx = -1e30f;
    #pragma unroll
    for (int mt = 0; mt < 4; ++mt)
      #pragma unroll
      for (int rr = 0; rr < 4; ++rr) {
        const float v = s[mt][nt][rr] * tm;
        s[mt][nt][rr] = v;
        mx = fmaxf(mx, v);
      }
    mx = fmaxf(mx, __shfl_xor(mx, 16));
    mx = fmaxf(mx, __shfl_xor(mx, 32));
    float sum = 0.f;
    #pragma unroll
    for (int mt = 0; mt < 4; ++mt)
      #pragma unroll
      for (int rr = 0; rr < 4; ++rr) {
        const float p = __expf(s[mt][nt][rr] - mx);
        s[mt][nt][rr] = p;
        sum += p;
      }
    sum += __shfl_xor(sum, 16);
    sum += __shfl_xor(sum, 32);
    const float ri = 1.f / sum;
    #pragma unroll
    for (int mt = 0; mt < 4; ++mt) Pb[mt][nt] = cvt4(s[mt][nt], ri);
  }
  f32x4 pcd[2][4];
  #pragma unroll
  for (int dj = 0; dj < 2; ++dj)
    #pragma unroll
    for (int nt = 0; nt < 4; ++nt) pcd[dj][nt] = fzero;
  #pragma unroll
  for (int mt = 0; mt < 4; ++mt)
    #pragma unroll
    for (int dj = 0; dj < 2; ++dj) {
      const int d = dj * 16 + l15;
      const unsigned ad = VB + (unsigned)(d * 128 + (((mt * 2 + (g >> 1)) ^ (d & 7)) << 4) + (g & 1) * 8);
      const bf16x4 vf = *(const bf16x4*)(smem + ad);
      #pragma unroll
      for (int nt = 0; nt < 4; ++nt)
        pcd[dj][nt] = MFMA_K16(vf, Pb[mt][nt], pcd[dj][nt]);
    }
  __syncthreads();
  #pragma unroll
  for (int dj = 0; dj < 2; ++dj)
    #pragma unroll
    for (int nt = 0; nt < 4; ++nt) {
      const bf16x4 q = cvt4(pcd[dj][nt], 1.f);
      const int pos = nt * 16 + l15;
      const int c0 = h * 32 + dj * 16 + 4 * g;
      const unsigned ad = (unsigned)(pos * 512 + (((c0 >> 3) ^ PI(pos)) << 4) + (c0 & 7) * 2);
      *(bf16x4*)(smem + ad) = q;
    }
  __syncthreads();
  f32x4 ocd[4][2];
  #pragma unroll
  for (int nt = 0; nt < 4; ++nt) { ocd[nt][0] = fzero; ocd[nt][1] = fzero; }
  {
    bf16x8 w0 = ldw8<WB16>(Wo, wv * 32 + l15,      g * 8);
    bf16x8 w1 = ldw8<WB16>(Wo, wv * 32 + 16 + l15, g * 8);
    #pragma unroll
    for (int ks = 0; ks < 8; ++ks) {
      bf16x8 n0, n1;
      if (ks < 7) {
        n0 = ldw8<WB16>(Wo, wv * 32 + l15,      (ks + 1) * 32 + g * 8);
        n1 = ldw8<WB16>(Wo, wv * 32 + 16 + l15, (ks + 1) * 32 + g * 8);
      }
      #pragma unroll
      for (int nt = 0; nt < 4; ++nt) {
        const int pos = nt * 16 + l15;
        const unsigned ad = (unsigned)(pos * 512 + (((ks * 4 + g) ^ PI(pos)) << 4));
        const bf16x8 af = *(const bf16x8*)(smem + ad);
        ocd[nt][0] = MFMA_K32(af, w0, ocd[nt][0]);
        ocd[nt][1] = MFMA_K32(af, w1, ocd[nt][1]);
      }
      if (ks < 7) { w0 = n0; w1 = n1; }
    }
  }
  #pragma unroll
  for (int nt = 0; nt < 4; ++nt)
    #pragma unroll
    for (int ctj = 0; ctj < 2; ++ctj) {
      const int c_out = wv * 32 + ctj * 16 + l15;
      const int h_out = nt * 2 + (g >> 1);
      const int w0o = 4 * (g & 1);
      float4 v;
      v.x = ocd[nt][ctj][0]; v.y = ocd[nt][ctj][1];
      v.z = ocd[nt][ctj][2]; v.w = ocd[nt][ctj][3];
      *(float4*)(out + ibase + (size_t)c_out * 36864 + (size_t)(xoff + h_out * 192 + w0o)) = v;
    }
}

extern "C" void kernel_launch(void* const* d_in, const int* in_sizes, int n_in,
                              void* d_out, int out_size, void* d_ws, size_t ws_size,
                              hipStream_t stream) {
  (void)in_sizes; (void)n_in; (void)out_size;
  const float* xq   = (const float*)d_in[0];
  const float* xkv  = (const float*)d_in[1];
  const float* temp = (const float*)d_in[2];
  const float* Wq   = (const float*)d_in[3];
  const float* Wk   = (const float*)d_in[4];
  const float* Wv   = (const float*)d_in[5];
  const float* Wo   = (const float*)d_in[6];
  float* out = (float*)d_out;

  const size_t W_ELEMS = 262144;                 // 4 x 256 x 256 bf16 weights
  auto need = [&](int nb) {
    return (W_ELEMS + 5u * (size_t)nb * BUFE) * sizeof(ushort_t);
  };
  ushort_t* wsb = (ushort_t*)d_ws;

  auto run = [&](int bbase, int nb) {
    ushort_t* base = wsb + W_ELEMS;
    ushort_t* xtq  = base;
    ushort_t* xtkv = xtq  + (size_t)nb * BUFE;
    ushort_t* qb   = xtkv + (size_t)nb * BUFE;   // also a-buffer (alias)
    ushort_t* kb   = qb   + (size_t)nb * BUFE;
    ushort_t* vb   = kb   + (size_t)nb * BUFE;
    g0_xt<<<dim3(nb * 4608), dim3(256), 0, stream>>>(xq, xkv, xtq, xtkv, bbase);
    g1_qkv<<<dim3(nb * 2304), dim3(256), 0, stream>>>(
        xtq, xtkv, wsb, wsb + 65536, wsb + 131072, qb, kb, vb);
    attn2<<<dim3(nb * 1152), dim3(256), 0, stream>>>(temp, qb, kb, vb, qb);
    k2_out<<<dim3(nb * 768), dim3(256), 0, stream>>>(wsb + 196608, qb, out, bbase);
  };

  if (ws_size >= need(2)) {
    wconv<<<dim3(256), dim3(256), 0, stream>>>(Wq, Wk, Wv, Wo, wsb);
    run(0, 2);
  } else if (ws_size >= need(1)) {
    wconv<<<dim3(256), dim3(256), 0, stream>>>(Wq, Wk, Wv, Wo, wsb);
    run(0, 1);
    run(1, 1);
  } else if (ws_size >= W_ELEMS * sizeof(ushort_t)) {
    wconv<<<dim3(256), dim3(256), 0, stream>>>(Wq, Wk, Wv, Wo, wsb);
    (void)hipFuncSetAttribute((const void*)&wsmdta_old<true>,
                              hipFuncAttributeMaxDynamicSharedMemorySize, SMEM_OLD);
    wsmdta_old<true><<<dim3(1152), dim3(512), SMEM_OLD, stream>>>(
        xq, xkv, temp, wsb, wsb + 65536, wsb + 131072, wsb + 196608, out);
  } else {
    (void)hipFuncSetAttribute((const void*)&wsmdta_old<false>,
                              hipFuncAttributeMaxDynamicSharedMemorySize, SMEM_OLD);
    wsmdta_old<false><<<dim3(1152), dim3(512), SMEM_OLD, stream>>>(
        xq, xkv, temp, Wq, Wk, Wv, Wo, out);
  }
}

// Round 18
// 183.633 us; speedup vs baseline: 2.2606x; 2.2606x over previous
//
#include <hip/hip_runtime.h>
#include <hip/hip_bf16.h>

// ---------------------------------------------------------------------------
// WindowShiftedMDTA, v18 == v16/v14 final (MI355X / gfx950).
//
// Math fact: with shift = window/2 the reference's shift-mask is all ones =>
// output == unshifted branch only.  fp32 I/O, bf16 MFMA compute (validated:
// absmax 4.9e-4 vs threshold 1.79e-3).
//
// v17 post-mortem: __launch_bounds__(256,6) made regalloc squeeze g1 to
// 40 VGPR -> accumulator spills (WRITE 668MB) -> 415us.  Third spill event:
// 64 VGPR @ 4 blocks/CU is the local optimum; occupancy raises re-run
// regalloc with a tighter budget and are NOT minimal-risk.
// v18 = exact revert to the validated 184.5us v16 pipeline:
//   wconv -> g0_xt -> g1_qkv (xT-staged, weight-hoist, stash-stores) ->
//   attn2 (LDS-free) -> k2_out; nb=1 two-pass; v6 fallback chain.
// ---------------------------------------------------------------------------

typedef short bf16x4 __attribute__((ext_vector_type(4)));
typedef short bf16x8 __attribute__((ext_vector_type(8)));
typedef float f32x4  __attribute__((ext_vector_type(4)));
typedef unsigned short ushort_t;

#define MFMA_K16(A_, B_, C_) __builtin_amdgcn_mfma_f32_16x16x16bf16_1k((A_), (B_), (C_), 0, 0, 0)
#define MFMA_K32(A_, B_, C_) __builtin_amdgcn_mfma_f32_16x16x32_bf16((A_), (B_), (C_), 0, 0, 0)

__device__ __forceinline__ short f2b(float f) {
  __hip_bfloat16 h = __float2bfloat16(f);
  return __builtin_bit_cast(short, h);
}
__device__ __forceinline__ bf16x4 cvt4(f32x4 v, float sc) {
  bf16x4 r;
  r[0] = f2b(v[0] * sc); r[1] = f2b(v[1] * sc);
  r[2] = f2b(v[2] * sc); r[3] = f2b(v[3] * sc);
  return r;
}
__device__ __forceinline__ int PI(int p) { return (p ^ (p >> 3)) & 7; }

template<bool B16>
__device__ __forceinline__ bf16x8 ldw8(const void* W, int row, int c0) {
  if constexpr (B16) {
    return *(const bf16x8*)((const ushort_t*)W + (row << 8) + c0);
  } else {
    const float* p = (const float*)W + (row << 8) + c0;
    const float4 x = *(const float4*)p, y = *(const float4*)(p + 4);
    bf16x8 f;
    f[0] = f2b(x.x); f[1] = f2b(x.y); f[2] = f2b(x.z); f[3] = f2b(x.w);
    f[4] = f2b(y.x); f[5] = f2b(y.y); f[6] = f2b(y.z); f[7] = f2b(y.w);
    return f;
  }
}
__device__ __forceinline__ bf16x8 ldw8b(const ushort_t* W, int row, int c0) {
  return *(const bf16x8*)(W + (row << 8) + c0);
}

constexpr size_t BUFE = 9437184;                 // 256 c x 36864 px (1 batch)

__global__ void wconv(const float* __restrict__ a, const float* __restrict__ b,
                      const float* __restrict__ c, const float* __restrict__ d,
                      ushort_t* __restrict__ o) {
  const int gid = blockIdx.x * 256 + threadIdx.x;
  const int which = gid >> 14;
  const int idx = (gid & 16383) * 4;
  const float* src = which == 0 ? a : which == 1 ? b : which == 2 ? c : d;
  const float4 v = *(const float4*)(src + idx);
  bf16x4 w; w[0] = f2b(v.x); w[1] = f2b(v.y); w[2] = f2b(v.z); w[3] = f2b(v.w);
  *(bf16x4*)(o + which * 65536 + idx) = w;
}

// ======================= g0_xt: x [c][px] f32 -> xT [px][c] bf16 ===========
__global__ __launch_bounds__(256, 4) void g0_xt(
    const float* __restrict__ xq, const float* __restrict__ xkv,
    ushort_t* __restrict__ xtq, ushort_t* __restrict__ xtkv, int bbase)
{
  __shared__ __align__(16) ushort_t tile[64 * 72];
  const int tid = threadIdx.x;
  const int id = (blockIdx.x & 7) * (gridDim.x >> 3) + (blockIdx.x >> 3);
  int r = id;
  const int pxt = r % 576; r /= 576;
  const int ct = r & 3; r >>= 2;
  const int which = r & 1;
  const int bl = r >> 1;
  const float* src = which ? xkv : xq;
  ushort_t* dst = which ? xtkv : xtq;
  const size_t gib = (size_t)(bbase + bl) * BUFE;

  {
    const int cr = tid >> 2, seg = tid & 3;
    const float* p = src + gib + (size_t)(ct * 64 + cr) * 36864 + pxt * 64 + seg * 16;
    const float4 f0 = *(const float4*)p,       f1 = *(const float4*)(p + 4);
    const float4 f2 = *(const float4*)(p + 8), f3 = *(const float4*)(p + 12);
    bf16x8 a, b;
    a[0]=f2b(f0.x); a[1]=f2b(f0.y); a[2]=f2b(f0.z); a[3]=f2b(f0.w);
    a[4]=f2b(f1.x); a[5]=f2b(f1.y); a[6]=f2b(f1.z); a[7]=f2b(f1.w);
    b[0]=f2b(f2.x); b[1]=f2b(f2.y); b[2]=f2b(f2.z); b[3]=f2b(f2.w);
    b[4]=f2b(f3.x); b[5]=f2b(f3.y); b[6]=f2b(f3.z); b[7]=f2b(f3.w);
    *(bf16x8*)(tile + cr * 72 + seg * 16) = a;
    *(bf16x8*)(tile + cr * 72 + seg * 16 + 8) = b;
  }
  __syncthreads();
  {
    const int opx = tid >> 2, oseg = tid & 3;
    bf16x8 a, b;
    #pragma unroll
    for (int j = 0; j < 8; ++j) a[j] = tile[(oseg * 16 + j) * 72 + opx];
    #pragma unroll
    for (int j = 0; j < 8; ++j) b[j] = tile[(oseg * 16 + 8 + j) * 72 + opx];
    ushort_t* q = dst + (size_t)bl * BUFE + (size_t)(pxt * 64 + opx) * 256 + ct * 64 + oseg * 16;
    *(bf16x8*)q = a;
    *(bf16x8*)(q + 8) = b;
  }
}

// ======================= g1_qkv: q,k,v = W . x =============================
__global__ __launch_bounds__(256, 4) void g1_qkv(
    const ushort_t* __restrict__ xtq, const ushort_t* __restrict__ xtkv,
    const ushort_t* __restrict__ Wq, const ushort_t* __restrict__ Wk,
    const ushort_t* __restrict__ Wv,
    ushort_t* __restrict__ qbuf, ushort_t* __restrict__ kbuf,
    ushort_t* __restrict__ vimg)
{
  __shared__ __align__(16) char smem[26624];     // stage 24576 | v-stash 26624
  const int tid = threadIdx.x, lane = tid & 63, wv4 = tid >> 6;
  const int l15 = lane & 15, g = lane >> 4;

  const int wid = (blockIdx.x & 7) * (gridDim.x >> 3) + (blockIdx.x >> 3);
  const int ct = wid % 6;
  int r = wid / 6;
  const int whalf = r & 1; r >>= 1;
  const int h = r % 192;
  const int bl = r / 192;
  const int ph = h & 7;
  const int winbase = bl * 576 + (h >> 3) * 24 + whalf * 12;
  const int pxrow = h * 192 + whalf * 96;

  const int mode = ct >> 1;                      // 0=q,1=k,2=v
  const ushort_t* xs = ((mode == 0) ? xtq : xtkv) + (size_t)bl * BUFE;
  const ushort_t* W  = (mode == 0) ? Wq : (mode == 1) ? Wk : Wv;
  const int chalf = (ct & 1) * 128;
  const int cobase = chalf + wv4 * 32;

  f32x4 acc[6][2];
  #pragma unroll
  for (int nt = 0; nt < 6; ++nt) { acc[nt][0] = {0,0,0,0}; acc[nt][1] = {0,0,0,0}; }

  #pragma unroll
  for (int ki = 0; ki < 2; ++ki) {
    bf16x8 wf[4][2];
    #pragma unroll
    for (int sk = 0; sk < 4; ++sk) {
      const int c0 = ki * 128 + sk * 32 + g * 8;
      wf[sk][0] = ldw8b(W, cobase + l15,      c0);
      wf[sk][1] = ldw8b(W, cobase + 16 + l15, c0);
    }
    if (ki) __syncthreads();
    #pragma unroll
    for (int j = 0; j < 6; ++j) {
      const int u = j * 256 + tid;
      const int t = u >> 4, ch = u & 15;
      const bf16x8 v = *(const bf16x8*)(xs + (size_t)(pxrow + t) * 256 + ki * 128 + ch * 8);
      const int sl = ch ^ (t & 7);
      *(bf16x8*)(smem + (unsigned)(t * 256 + sl * 16)) = v;
    }
    __syncthreads();
    #pragma unroll
    for (int sk = 0; sk < 4; ++sk) {
      #pragma unroll
      for (int nt = 0; nt < 6; ++nt) {
        const int t = nt * 16 + l15;
        const int lch = sk * 4 + g;
        const bf16x8 af = *(const bf16x8*)(smem + (unsigned)(t * 256 + ((lch ^ (t & 7)) << 4)));
        if (mode < 2) {
          acc[nt][0] = MFMA_K32(wf[sk][0], af, acc[nt][0]);  // C: col=px, rows=co
          acc[nt][1] = MFMA_K32(wf[sk][1], af, acc[nt][1]);
        } else {
          acc[nt][0] = MFMA_K32(af, wf[sk][0], acc[nt][0]);  // C: col=d, rows=px
          acc[nt][1] = MFMA_K32(af, wf[sk][1], acc[nt][1]);
        }
      }
    }
  }
  __syncthreads();                               // LDS tile now dead -> stash

  if (mode < 2) {
    #pragma unroll
    for (int nt = 0; nt < 6; ++nt)
      #pragma unroll
      for (int cj = 0; cj < 2; ++cj) {
        const int t = nt * 16 + l15;
        const int bb = (wv4 * 4 + cj * 2 + (g >> 1)) ^ (t & 7);
        *(bf16x4*)(smem + (unsigned)(t * 256 + bb * 16 + (g & 1) * 8)) = cvt4(acc[nt][cj], 1.f);
      }
    __syncthreads();
    ushort_t* dst = (mode == 0) ? qbuf : kbuf;
    #pragma unroll
    for (int j = 0; j < 6; ++j) {
      const int u = j * 256 + tid;
      const int t = u >> 4, ch = u & 15;
      const bf16x8 v = *(const bf16x8*)(smem + (unsigned)(t * 256 + ((ch ^ (t & 7)) << 4)));
      const int win = winbase + (t >> 3);
      const int pos = ph * 8 + (t & 7);
      *(bf16x8*)(dst + (size_t)win * 16384 + pos * 256 + chalf + ch * 8) = v;
    }
  } else {
    #pragma unroll
    for (int nt = 0; nt < 6; ++nt)
      #pragma unroll
      for (int dj = 0; dj < 2; ++dj) {
        const int dl = wv4 * 32 + dj * 16 + l15;
        *(bf16x4*)(smem + (unsigned)(dl * 208 + (nt * 16 + 4 * g) * 2)) = cvt4(acc[nt][dj], 1.f);
      }
    __syncthreads();
    #pragma unroll
    for (int j = 0; j < 6; ++j) {
      const int u = j * 256 + tid;
      const int dl = u / 12, ch = u - dl * 12;
      const bf16x8 v = *(const bf16x8*)(smem + (unsigned)(dl * 208 + ch * 16));
      *(bf16x8*)(vimg + (size_t)bl * BUFE + (size_t)(chalf + dl) * 36864 + pxrow + ch * 8) = v;
    }
  }
}

// ======================= attn2: per-(win,head) attention ===================
__global__ __launch_bounds__(256, 4) void attn2(
    const float* __restrict__ temp,
    const ushort_t* __restrict__ qbuf, const ushort_t* __restrict__ kbuf,
    const ushort_t* __restrict__ vimg, ushort_t* __restrict__ abuf)
{
  const int tid = threadIdx.x, lane = tid & 63, wv4 = tid >> 6;
  const int l15 = lane & 15, g = lane >> 4;

  const int wid = (blockIdx.x & 7) * (gridDim.x >> 3) + (blockIdx.x >> 3);
  const int hg = wid & 1;
  const int winL = wid >> 1;
  const int bl = winL / 576, rw = winL % 576;
  const int wh = rw / 24, ww = rw % 24;
  const int h = hg * 4 + wv4;
  const float tm = temp[h];
  const size_t wb = (size_t)winL * 16384;
  const int hb = h * 32;
  const f32x4 fzero = {0.f, 0.f, 0.f, 0.f};

  bf16x8 qf[4], kf[4];
  #pragma unroll
  for (int i = 0; i < 4; ++i) {
    qf[i] = *(const bf16x8*)(qbuf + wb + (i * 16 + l15) * 256 + hb + g * 8);
    kf[i] = *(const bf16x8*)(kbuf + wb + (i * 16 + l15) * 256 + hb + g * 8);
  }
  f32x4 s[4][4];
  #pragma unroll
  for (int mt = 0; mt < 4; ++mt)
    #pragma unroll
    for (int nt = 0; nt < 4; ++nt)
      s[mt][nt] = MFMA_K32(kf[mt], qf[nt], fzero);   // C[m][n], col=n

  bf16x4 Pb[4][4];
  #pragma unroll
  for (int nt = 0; nt < 4; ++nt) {
    float mx = -1e30f;
    #pragma unroll
    for (int mt = 0; mt < 4; ++mt)
      #pragma unroll
      for (int rr = 0; rr < 4; ++rr) {
        const float v = s[mt][nt][rr] * tm;
        s[mt][nt][rr] = v;
        mx = fmaxf(mx, v);
      }
    mx = fmaxf(mx, __shfl_xor(mx, 16));
    mx = fmaxf(mx, __shfl_xor(mx, 32));
    float sum = 0.f;
    #pragma unroll
    for (int mt = 0; mt < 4; ++mt)
      #pragma unroll
      for (int rr = 0; rr < 4; ++rr) {
        const float p = __expf(s[mt][nt][rr] - mx);
        s[mt][nt][rr] = p;
        sum += p;
      }
    sum += __shfl_xor(sum, 16);
    sum += __shfl_xor(sum, 32);
    const float ri = 1.f / sum;
    #pragma unroll
    for (int mt = 0; mt < 4; ++mt) Pb[mt][nt] = cvt4(s[mt][nt], ri);
  }

  f32x4 pcd[2][4];
  #pragma unroll
  for (int dj = 0; dj < 2; ++dj)
    #pragma unroll
    for (int nt = 0; nt < 4; ++nt) pcd[dj][nt] = fzero;
  #pragma unroll
  for (int mt = 0; mt < 4; ++mt)
    #pragma unroll
    for (int dj = 0; dj < 2; ++dj) {
      const int d = hb + dj * 16 + l15;
      const bf16x4 vf = *(const bf16x4*)(vimg + (size_t)bl * BUFE + (size_t)d * 36864
                        + (wh * 8 + 2 * mt + (g >> 1)) * 192 + ww * 8 + 4 * (g & 1));
      #pragma unroll
      for (int nt = 0; nt < 4; ++nt)
        pcd[dj][nt] = MFMA_K16(vf, Pb[mt][nt], pcd[dj][nt]);  // C[d][n]
    }

  #pragma unroll
  for (int dj = 0; dj < 2; ++dj)
    #pragma unroll
    for (int nt = 0; nt < 4; ++nt) {
      const int pos = nt * 16 + l15;
      const int c0 = hb + dj * 16 + 4 * g;
      *(bf16x4*)(abuf + wb + pos * 256 + c0) = cvt4(pcd[dj][nt], 1.f);
    }
}

// ======================= k2: out = Wo . A (image layout) ===================
__global__ __launch_bounds__(256, 4) void k2_out(
    const ushort_t* __restrict__ Wo, const ushort_t* __restrict__ abuf,
    float* __restrict__ out, int bbase)
{
  __shared__ __align__(16) char smem[24576];
  const int tid = threadIdx.x, lane = tid & 63, wv4 = tid >> 6;
  const int l15 = lane & 15, g = lane >> 4;

  const int wid = (blockIdx.x & 7) * (gridDim.x >> 3) + (blockIdx.x >> 3);
  const int ct = wid & 1;
  int r = wid >> 1;
  const int whalf = r & 1; r >>= 1;
  const int h = r % 192, bl = r / 192;
  const int wh = h >> 3, ph = h & 7, wstart = whalf * 96;
  const int winbase = bl * 576 + wh * 24 + (wstart >> 3);

  f32x4 acc[6][2];
  #pragma unroll
  for (int nt = 0; nt < 6; ++nt) { acc[nt][0] = {0,0,0,0}; acc[nt][1] = {0,0,0,0}; }

  const int corow0 = ct * 128 + wv4 * 32 + l15;

  #pragma unroll
  for (int ki = 0; ki < 2; ++ki) {
    const int kb = ki * 128;
    if (ki) __syncthreads();
    #pragma unroll
    for (int j = 0; j < 6; ++j) {
      const int u = j * 256 + tid;
      const int t = u >> 4, ch = u & 15;
      const int win = winbase + (t >> 3);
      const int wpos = ph * 8 + (t & 7);
      const bf16x8 v = *(const bf16x8*)(abuf + (size_t)win * 16384 + wpos * 256 + kb + ch * 8);
      const int sl = ch ^ (t & 7);
      *(bf16x8*)(smem + (unsigned)(t * 256 + sl * 16)) = v;
    }
    __syncthreads();
    #pragma unroll
    for (int sk = 0; sk < 4; ++sk) {
      const int c0 = kb + sk * 32 + g * 8;
      const bf16x8 w0 = ldw8b(Wo, corow0,      c0);
      const bf16x8 w1 = ldw8b(Wo, corow0 + 16, c0);
      #pragma unroll
      for (int nt = 0; nt < 6; ++nt) {
        const int t = nt * 16 + l15;
        const int lch = sk * 4 + g;
        const bf16x8 af = *(const bf16x8*)(smem + (unsigned)(t * 256 + ((lch ^ (t & 7)) << 4)));
        acc[nt][0] = MFMA_K32(w0, af, acc[nt][0]);
        acc[nt][1] = MFMA_K32(w1, af, acc[nt][1]);
      }
    }
  }

  #pragma unroll
  for (int nt = 0; nt < 6; ++nt)
    #pragma unroll
    for (int cj = 0; cj < 2; ++cj) {
      const int t = nt * 16 + l15;
      #pragma unroll
      for (int rr = 0; rr < 4; ++rr) {
        const int co = ct * 128 + wv4 * 32 + cj * 16 + 4 * g + rr;
        out[(size_t)(bbase + bl) * BUFE + (size_t)co * 36864 + h * 192 + wstart + t]
            = acc[nt][cj][rr];
      }
    }
}

// ================= v6 fallback (validated, 276us) ==========================
constexpr int SMEM_OLD = 65536;

template<int NT>
__device__ __forceinline__ void stage_half(char* dst, const float* __restrict__ src,
                                           int coff, int tid, size_t ibase, int xoff) {
  #pragma unroll
  for (int j = 0; j < 1024 / NT; ++j) {
    const int u = j * NT + tid;
    const int c = u >> 3, hr = u & 7;
    const size_t gg = ibase + (size_t)(c + coff) * 36864 + (size_t)(xoff + hr * 192);
    const float4 a0 = *(const float4*)(src + gg);
    const float4 a1 = *(const float4*)(src + gg + 4);
    const float vv[8] = {a0.x, a0.y, a0.z, a0.w, a1.x, a1.y, a1.z, a1.w};
    #pragma unroll
    for (int w = 0; w < 8; ++w) {
      const int pos = hr * 8 + w;
      const unsigned ad = (unsigned)(pos * 256 + (((c >> 3) ^ PI(pos)) << 4) + (c & 7) * 2);
      *(short*)(dst + ad) = f2b(vv[w]);
    }
  }
}
__device__ __forceinline__ bf16x8 xfrag8(const char* base, int kt, int nt, int l15, int g) {
  const int pos = nt * 16 + l15;
  const int c0 = kt * 32 + g * 8;
  const unsigned ad = (unsigned)(pos * 256 + (((c0 >> 3) ^ PI(pos)) << 4));
  return *(const bf16x8*)(base + ad);
}

template<bool WB16>
__global__ __launch_bounds__(512, 4) void wsmdta_old(
    const float* __restrict__ xq, const float* __restrict__ xkv,
    const float* __restrict__ temp,
    const void* __restrict__ Wq, const void* __restrict__ Wk,
    const void* __restrict__ Wv, const void* __restrict__ Wo,
    float* __restrict__ out)
{
  extern __shared__ __align__(16) char smem[];
  const int tid = threadIdx.x, lane = tid & 63, wv = tid >> 6;
  const int l15 = lane & 15, g = lane >> 4;
  const int bid = blockIdx.x;
  const int wid = (bid & 7) * 144 + (bid >> 3);
  const int b  = wid / 576, rw = wid - b * 576;
  const int wh = rw / 24,   ww = rw - wh * 24;
  const int xoff = wh * 1536 + ww * 8;
  const size_t ibase = (size_t)b * BUFE;
  const unsigned VB = 32768u + (unsigned)wv * 4096u;
  const f32x4 fzero = {0.f, 0.f, 0.f, 0.f};
  const int h = wv;
  const float tm = temp[h];

  f32x4 qcd[2][4];
  #pragma unroll
  for (int dj = 0; dj < 2; ++dj)
    #pragma unroll
    for (int nt = 0; nt < 4; ++nt) qcd[dj][nt] = fzero;
  #pragma unroll
  for (int half = 0; half < 2; ++half) {
    if (half) __syncthreads();
    stage_half<512>(smem, xq, half * 128, tid, ibase, xoff);
    __syncthreads();
    const int cg = half * 128;
    #pragma unroll
    for (int kt = 0; kt < 4; ++kt) {
      const bf16x8 w0 = ldw8<WB16>(Wq, h * 32 + l15,      cg + kt * 32 + g * 8);
      const bf16x8 w1 = ldw8<WB16>(Wq, h * 32 + 16 + l15, cg + kt * 32 + g * 8);
      #pragma unroll
      for (int nt = 0; nt < 4; ++nt) {
        const bf16x8 xf = xfrag8(smem, kt, nt, l15, g);
        qcd[0][nt] = MFMA_K32(w0, xf, qcd[0][nt]);
        qcd[1][nt] = MFMA_K32(w1, xf, qcd[1][nt]);
      }
    }
    __syncthreads();
  }
  bf16x4 qb[2][4];
  #pragma unroll
  for (int dj = 0; dj < 2; ++dj)
    #pragma unroll
    for (int nt = 0; nt < 4; ++nt) qb[dj][nt] = cvt4(qcd[dj][nt], 1.f);

  f32x4 kcd[2][4], vcd[2][4];
  #pragma unroll
  for (int dj = 0; dj < 2; ++dj)
    #pragma unroll
    for (int nt = 0; nt < 4; ++nt) { kcd[dj][nt] = fzero; vcd[dj][nt] = fzero; }
  #pragma unroll
  for (int half = 0; half < 2; ++half) {
    stage_half<512>(smem, xkv, half * 128, tid, ibase, xoff);
    __syncthreads();
    const int cg = half * 128;
    #pragma unroll
    for (int kt = 0; kt < 4; ++kt) {
      const bf16x8 wk0 = ldw8<WB16>(Wk, h * 32 + l15,      cg + kt * 32 + g * 8);
      const bf16x8 wk1 = ldw8<WB16>(Wk, h * 32 + 16 + l15, cg + kt * 32 + g * 8);
      const bf16x8 wv0 = ldw8<WB16>(Wv, h * 32 + l15,      cg + kt * 32 + g * 8);
      const bf16x8 wv1 = ldw8<WB16>(Wv, h * 32 + 16 + l15, cg + kt * 32 + g * 8);
      #pragma unroll
      for (int np = 0; np < 2; ++np) {
        const bf16x8 xf0 = xfrag8(smem, kt, np * 2,     l15, g);
        const bf16x8 xf1 = xfrag8(smem, kt, np * 2 + 1, l15, g);
        kcd[0][np*2]   = MFMA_K32(wk0, xf0, kcd[0][np*2]);
        kcd[1][np*2]   = MFMA_K32(wk1, xf0, kcd[1][np*2]);
        vcd[0][np*2]   = MFMA_K32(wv0, xf0, vcd[0][np*2]);
        vcd[1][np*2]   = MFMA_K32(wv1, xf0, vcd[1][np*2]);
        kcd[0][np*2+1] = MFMA_K32(wk0, xf1, kcd[0][np*2+1]);
        kcd[1][np*2+1] = MFMA_K32(wk1, xf1, kcd[1][np*2+1]);
        vcd[0][np*2+1] = MFMA_K32(wv0, xf1, vcd[0][np*2+1]);
        vcd[1][np*2+1] = MFMA_K32(wv1, xf1, vcd[1][np*2+1]);
      }
    }
    if (half == 0) __syncthreads();
  }
  bf16x4 kb[2][4];
  #pragma unroll
  for (int dj = 0; dj < 2; ++dj)
    #pragma unroll
    for (int mt = 0; mt < 4; ++mt) kb[dj][mt] = cvt4(kcd[dj][mt], 1.f);
  #pragma unroll
  for (int dj = 0; dj < 2; ++dj)
    #pragma unroll
    for (int mt = 0; mt < 4; ++mt) {
      const bf16x4 q = cvt4(vcd[dj][mt], 1.f);
      const int m = mt * 16 + l15;
      #pragma unroll
      for (int rr = 0; rr < 4; ++rr) {
        const int d = dj * 16 + 4 * g + rr;
        const unsigned ad = VB + (unsigned)(d * 128 + (((m >> 3) ^ (d & 7)) << 4) + (m & 7) * 2);
        *(short*)(smem + ad) = q[rr];
      }
    }
  f32x4 s[4][4];
  #pragma unroll
  for (int mt = 0; mt < 4; ++mt)
    #pragma unroll
    for (int nt = 0; nt < 4; ++nt) {
      s[mt][nt] = MFMA_K16(kb[0][mt], qb[0][nt], fzero);
      s[mt][nt] = MFMA_K16(kb[1][mt], qb[1][nt], s[mt][nt]);
    }
  bf16x4 Pb[4][4];
  #pragma unroll
  for (int nt = 0; nt < 4; ++nt) {
    float mx = -1e30f;
    #pragma unroll
    for (int mt = 0; mt < 4; ++mt)
      #pragma unroll
      for (int rr = 0; rr < 4; ++rr) {
        const float v = s[mt][nt][rr] * tm;
        s[mt][nt][rr] = v;
        mx = fmaxf(mx, v);
      }
    mx = fmaxf(mx, __shfl_xor(mx, 16));
    mx = fmaxf(mx, __shfl_xor(mx, 32));
    float sum = 0.f;
    #pragma unroll
    for (int mt = 0; mt < 4; ++mt)
      #pragma unroll
      for (int rr = 0; rr < 4; ++rr) {
        const float p = __expf(s[mt][nt][rr] - mx);
        s[mt][nt][rr] = p;
        sum += p;
      }
    sum += __shfl_xor(sum, 16);
    sum += __shfl_xor(sum, 32);
    const float ri = 1.f / sum;
    #pragma unroll
    for (int mt = 0; mt < 4; ++mt) Pb[mt][nt] = cvt4(s[mt][nt], ri);
  }
  f32x4 pcd[2][4];
  #pragma unroll
  for (int dj = 0; dj < 2; ++dj)
    #pragma unroll
    for (int nt = 0; nt < 4; ++nt) pcd[dj][nt] = fzero;
  #pragma unroll
  for (int mt = 0; mt < 4; ++mt)
    #pragma unroll
    for (int dj = 0; dj < 2; ++dj) {
      const int d = dj * 16 + l15;
      const unsigned ad = VB + (unsigned)(d * 128 + (((mt * 2 + (g >> 1)) ^ (d & 7)) << 4) + (g & 1) * 8);
      const bf16x4 vf = *(const bf16x4*)(smem + ad);
      #pragma unroll
      for (int nt = 0; nt < 4; ++nt)
        pcd[dj][nt] = MFMA_K16(vf, Pb[mt][nt], pcd[dj][nt]);
    }
  __syncthreads();
  #pragma unroll
  for (int dj = 0; dj < 2; ++dj)
    #pragma unroll
    for (int nt = 0; nt < 4; ++nt) {
      const bf16x4 q = cvt4(pcd[dj][nt], 1.f);
      const int pos = nt * 16 + l15;
      const int c0 = h * 32 + dj * 16 + 4 * g;
      const unsigned ad = (unsigned)(pos * 512 + (((c0 >> 3) ^ PI(pos)) << 4) + (c0 & 7) * 2);
      *(bf16x4*)(smem + ad) = q;
    }
  __syncthreads();
  f32x4 ocd[4][2];
  #pragma unroll
  for (int nt = 0; nt < 4; ++nt) { ocd[nt][0] = fzero; ocd[nt][1] = fzero; }
  {
    bf16x8 w0 = ldw8<WB16>(Wo, wv * 32 + l15,      g * 8);
    bf16x8 w1 = ldw8<WB16>(Wo, wv * 32 + 16 + l15, g * 8);
    #pragma unroll
    for (int ks = 0; ks < 8; ++ks) {
      bf16x8 n0, n1;
      if (ks < 7) {
        n0 = ldw8<WB16>(Wo, wv * 32 + l15,      (ks + 1) * 32 + g * 8);
        n1 = ldw8<WB16>(Wo, wv * 32 + 16 + l15, (ks + 1) * 32 + g * 8);
      }
      #pragma unroll
      for (int nt = 0; nt < 4; ++nt) {
        const int pos = nt * 16 + l15;
        const unsigned ad = (unsigned)(pos * 512 + (((ks * 4 + g) ^ PI(pos)) << 4));
        const bf16x8 af = *(const bf16x8*)(smem + ad);
        ocd[nt][0] = MFMA_K32(af, w0, ocd[nt][0]);
        ocd[nt][1] = MFMA_K32(af, w1, ocd[nt][1]);
      }
      if (ks < 7) { w0 = n0; w1 = n1; }
    }
  }
  #pragma unroll
  for (int nt = 0; nt < 4; ++nt)
    #pragma unroll
    for (int ctj = 0; ctj < 2; ++ctj) {
      const int c_out = wv * 32 + ctj * 16 + l15;
      const int h_out = nt * 2 + (g >> 1);
      const int w0o = 4 * (g & 1);
      float4 v;
      v.x = ocd[nt][ctj][0]; v.y = ocd[nt][ctj][1];
      v.z = ocd[nt][ctj][2]; v.w = ocd[nt][ctj][3];
      *(float4*)(out + ibase + (size_t)c_out * 36864 + (size_t)(xoff + h_out * 192 + w0o)) = v;
    }
}

extern "C" void kernel_launch(void* const* d_in, const int* in_sizes, int n_in,
                              void* d_out, int out_size, void* d_ws, size_t ws_size,
                              hipStream_t stream) {
  (void)in_sizes; (void)n_in; (void)out_size;
  const float* xq   = (const float*)d_in[0];
  const float* xkv  = (const float*)d_in[1];
  const float* temp = (const float*)d_in[2];
  const float* Wq   = (const float*)d_in[3];
  const float* Wk   = (const float*)d_in[4];
  const float* Wv   = (const float*)d_in[5];
  const float* Wo   = (const float*)d_in[6];
  float* out = (float*)d_out;

  const size_t W_ELEMS = 262144;                 // 4 x 256 x 256 bf16 weights
  auto need = [&](int nb) {
    return (W_ELEMS + 5u * (size_t)nb * BUFE) * sizeof(ushort_t);
  };
  ushort_t* wsb = (ushort_t*)d_ws;

  auto run = [&](int bbase, int nb) {
    ushort_t* base = wsb + W_ELEMS;
    ushort_t* xtq  = base;
    ushort_t* xtkv = xtq  + (size_t)nb * BUFE;
    ushort_t* qb   = xtkv + (size_t)nb * BUFE;   // also a-buffer (alias)
    ushort_t* kb   = qb   + (size_t)nb * BUFE;
    ushort_t* vb   = kb   + (size_t)nb * BUFE;
    g0_xt<<<dim3(nb * 4608), dim3(256), 0, stream>>>(xq, xkv, xtq, xtkv, bbase);
    g1_qkv<<<dim3(nb * 2304), dim3(256), 0, stream>>>(
        xtq, xtkv, wsb, wsb + 65536, wsb + 131072, qb, kb, vb);
    attn2<<<dim3(nb * 1152), dim3(256), 0, stream>>>(temp, qb, kb, vb, qb);
    k2_out<<<dim3(nb * 768), dim3(256), 0, stream>>>(wsb + 196608, qb, out, bbase);
  };

  if (ws_size >= need(2)) {
    wconv<<<dim3(256), dim3(256), 0, stream>>>(Wq, Wk, Wv, Wo, wsb);
    run(0, 2);
  } else if (ws_size >= need(1)) {
    wconv<<<dim3(256), dim3(256), 0, stream>>>(Wq, Wk, Wv, Wo, wsb);
    run(0, 1);
    run(1, 1);
  } else if (ws_size >= W_ELEMS * sizeof(ushort_t)) {
    wconv<<<dim3(256), dim3(256), 0, stream>>>(Wq, Wk, Wv, Wo, wsb);
    (void)hipFuncSetAttribute((const void*)&wsmdta_old<true>,
                              hipFuncAttributeMaxDynamicSharedMemorySize, SMEM_OLD);
    wsmdta_old<true><<<dim3(1152), dim3(512), SMEM_OLD, stream>>>(
        xq, xkv, temp, wsb, wsb + 65536, wsb + 131072, wsb + 196608, out);
  } else {
    (void)hipFuncSetAttribute((const void*)&wsmdta_old<false>,
                              hipFuncAttributeMaxDynamicSharedMemorySize, SMEM_OLD);
    wsmdta_old<false><<<dim3(1152), dim3(512), SMEM_OLD, stream>>>(
        xq, xkv, temp, Wq, Wk, Wv, Wo, out);
  }
}